// Round 15
// baseline (1257.503 us; speedup 1.0000x reference)
//
#include <hip/hip_runtime.h>
#include <math.h>

#define B_  64
#define T_  150
#define L_  256
#define H_  512
#define E_  512
#define V_  1000
#define G4_ 2048   // 4*H
#define DB_ 16     // producer blocks
#define NW_ 240    // worker blocks
#define HCB 32     // h-cols per producer block

typedef _Float16 f16;
typedef f16   f16x8 __attribute__((ext_vector_type(8)));
typedef f16   f16x4 __attribute__((ext_vector_type(4)));
typedef float f32x4 __attribute__((ext_vector_type(4)));
typedef unsigned long long ull;

__device__ __forceinline__ float sigmf(float x) { return 1.0f / (1.0f + expf(-x)); }

__device__ __forceinline__ ull aload(const ull* p)
{
    return __hip_atomic_load(p, __ATOMIC_RELAXED, __HIP_MEMORY_SCOPE_AGENT);
}

// =====================================================================
// Mega-kernel: 16 producers (R11 recurrence, xhist history) + 240 workers
// (t-chunked batched phase-2 with stage barriers).
// =====================================================================
__global__ __launch_bounds__(512) void mega_decoder(
    const int*   __restrict__ seq,      // [B][T]
    const float* __restrict__ G,        // [V][4H] pregate
    const float* __restrict__ Whh,      // [4H][H] fp32
    const float* __restrict__ cnn,      // [B][L][H] fp32
    const float* __restrict__ Whm,      // [512][512] fp32
    const float* __restrict__ Wom,      // [512][1024] fp32
    const float* __restrict__ Wlg,      // [1000][512] fp32
    const float* __restrict__ b_logit,  // [1000]
    ull*  __restrict__ xhist,           // [T+1][64][128] ull (fp16 h history)
    int*  __restrict__ tags,            // [16]
    int*  __restrict__ wflags,          // [240]
    f16*  __restrict__ stageA,          // [9600][512] f16 (mapped, then ctx)
    f16*  __restrict__ attP,            // [B][T][L] f16
    f16*  __restrict__ outv16,          // [9600][512] f16
    float* __restrict__ out)            // [B][T][V]
{
    __shared__ __align__(16) char smem[109568];

    const int tid = threadIdx.x;
    const int bx  = blockIdx.x;
    const int ln  = tid & 63;
    const int wv  = tid >> 6;

    if (bx < DB_) {
        // ================= PRODUCER (R11, hbuf dropped, history xh) =====
        f16   (*hlds)[520] = (f16(*)[520])smem;
        float (*glds)[132] = (float(*)[132])(smem + 66560);
        float (*csh)[36]   = (float(*)[36])(smem + 100352);
        const int bb  = bx;
        const int mh  = wv >> 2;
        const int nt2 = wv & 3;

        f16x8 bfr[2][16];
        #pragma unroll
        for (int j = 0; j < 2; ++j) {
            const int n = 2 * nt2 + j;
            const int grow = (n >> 1) * H_ + bb * HCB + (n & 1) * 16 + (ln & 15);
            #pragma unroll
            for (int kt = 0; kt < 16; ++kt) {
                const int k0 = kt * 32 + (ln >> 4) * 8;
                float4 w0 = *(const float4*)(Whh + (size_t)grow * H_ + k0);
                float4 w1 = *(const float4*)(Whh + (size_t)grow * H_ + k0 + 4);
                bfr[j][kt] = (f16x8){(f16)w0.x, (f16)w0.y, (f16)w0.z, (f16)w0.w,
                                     (f16)w1.x, (f16)w1.y, (f16)w1.z, (f16)w1.w};
            }
        }
        for (int e = tid; e < 64 * 520 / 4; e += 512) ((ull*)hlds)[e] = 0ull;
        for (int e = tid; e < 64 * 36; e += 512) ((float*)csh)[e] = 0.f;
        __syncthreads();

        const int cb = tid >> 3, cg = tid & 7;

        for (int t = 0; t < T_; ++t) {
            const int v = seq[cb * T_ + t];
            const float* gp = G + (size_t)v * G4_ + bb * HCB + cg * 4;
            float4 gq0 = *(const float4*)(gp);
            float4 gq1 = *(const float4*)(gp + H_);
            float4 gq2 = *(const float4*)(gp + 2 * H_);
            float4 gq3 = *(const float4*)(gp + 3 * H_);

            if (t > 0) {
                if (tid < DB_) {
                    while (__hip_atomic_load(&tags[tid], __ATOMIC_RELAXED,
                                             __HIP_MEMORY_SCOPE_AGENT) < t) {}
                }
                __syncthreads();
                const ull* src = xhist + (size_t)t * 8192;
                ull v0[8], v1[8];
                #pragma unroll
                for (int it = 0; it < 8; ++it) {
                    const int e = tid + it * 512;
                    const int b = e >> 6, s = e & 63;
                    v0[it] = aload(&src[b * 128 + 2 * s]);
                    v1[it] = aload(&src[b * 128 + 2 * s + 1]);
                }
                #pragma unroll
                for (int it = 0; it < 8; ++it) {
                    const int e = tid + it * 512;
                    const int b = e >> 6, s = e & 63;
                    ull* dst = (ull*)&hlds[b][s * 8];
                    dst[0] = v0[it]; dst[1] = v1[it];
                }
                __syncthreads();
            }

            f32x4 acc00 = {0.f,0.f,0.f,0.f}, acc01 = {0.f,0.f,0.f,0.f};
            f32x4 acc10 = {0.f,0.f,0.f,0.f}, acc11 = {0.f,0.f,0.f,0.f};
            #pragma unroll
            for (int kt = 0; kt < 16; ++kt) {
                const int ko = kt * 32 + (ln >> 4) * 8;
                f16x8 a0 = *(const f16x8*)&hlds[(2 * mh)     * 16 + (ln & 15)][ko];
                f16x8 a1 = *(const f16x8*)&hlds[(2 * mh + 1) * 16 + (ln & 15)][ko];
                acc00 = __builtin_amdgcn_mfma_f32_16x16x32_f16(a0, bfr[0][kt], acc00, 0, 0, 0);
                acc01 = __builtin_amdgcn_mfma_f32_16x16x32_f16(a0, bfr[1][kt], acc01, 0, 0, 0);
                acc10 = __builtin_amdgcn_mfma_f32_16x16x32_f16(a1, bfr[0][kt], acc10, 0, 0, 0);
                acc11 = __builtin_amdgcn_mfma_f32_16x16x32_f16(a1, bfr[1][kt], acc11, 0, 0, 0);
            }
            {
                const int r0 = (2 * mh) * 16 + (ln >> 4) * 4;
                const int r1 = (2 * mh + 1) * 16 + (ln >> 4) * 4;
                const int c0 = (2 * nt2) * 16 + (ln & 15);
                const int c1 = (2 * nt2 + 1) * 16 + (ln & 15);
                #pragma unroll
                for (int i = 0; i < 4; ++i) {
                    glds[r0 + i][c0] = acc00[i];
                    glds[r0 + i][c1] = acc01[i];
                    glds[r1 + i][c0] = acc10[i];
                    glds[r1 + i][c1] = acc11[i];
                }
            }
            __syncthreads();

            {
                float4 Gi = *(const float4*)&glds[cb][cg * 4];
                float4 Gf = *(const float4*)&glds[cb][32 + cg * 4];
                float4 Gg = *(const float4*)&glds[cb][64 + cg * 4];
                float4 Go = *(const float4*)&glds[cb][96 + cg * 4];
                float4 cold = *(const float4*)&csh[cb][cg * 4];
                float gi[4] = {Gi.x + gq0.x, Gi.y + gq0.y, Gi.z + gq0.z, Gi.w + gq0.w};
                float gf[4] = {Gf.x + gq1.x, Gf.y + gq1.y, Gf.z + gq1.z, Gf.w + gq1.w};
                float gg[4] = {Gg.x + gq2.x, Gg.y + gq2.y, Gg.z + gq2.z, Gg.w + gq2.w};
                float go[4] = {Go.x + gq3.x, Go.y + gq3.y, Go.z + gq3.z, Go.w + gq3.w};
                float cl[4] = {cold.x, cold.y, cold.z, cold.w};
                float4 cnew;
                f16x4 hp;
                #pragma unroll
                for (int i = 0; i < 4; ++i) {
                    float c2 = sigmf(gf[i]) * cl[i] + sigmf(gi[i]) * tanhf(gg[i]);
                    float h2 = sigmf(go[i]) * tanhf(c2);
                    ((float*)&cnew)[i] = c2;
                    hp[i] = (f16)h2;
                }
                *(float4*)&csh[cb][cg * 4] = cnew;
                __hip_atomic_store(
                    &xhist[(size_t)(t + 1) * 8192 + cb * 128 + bb * 8 + cg],
                    __builtin_bit_cast(ull, hp),
                    __ATOMIC_RELAXED, __HIP_MEMORY_SCOPE_AGENT);
            }
            __syncthreads();   // drains vmcnt before s_barrier
            if (tid == 0)
                __hip_atomic_store(&tags[bb], t + 1, __ATOMIC_RELAXED,
                                   __HIP_MEMORY_SCOPE_AGENT);
        }
        return;
    }

    // ================= WORKER =================
    const int wid = bx - DB_;
    f16   (*As)[40]  = (f16(*)[40])smem;                  //  5,120
    f16   (*Bs)[40]  = (f16(*)[40])(smem + 5120);         // 20,480 (256 rows)
    float (*sl)[260] = (float(*)[260])(smem + 25600);     // 66,560
    const int ln15 = ln & 15;
    const int lnk8 = (ln >> 4) * 8;
    const int lr4  = (ln >> 4) * 4;
    int epoch = 0;

    // worker barrier: flag-array (R8-validated), fences for normal-store stages
    auto wbar = [&](int ep) {
        __syncthreads();
        if (tid == 0) {
            __threadfence();
            __hip_atomic_store(&wflags[wid], ep, __ATOMIC_RELAXED,
                               __HIP_MEMORY_SCOPE_AGENT);
        }
        for (int i = tid; i < NW_; i += 512)
            while (__hip_atomic_load(&wflags[i], __ATOMIC_RELAXED,
                                     __HIP_MEMORY_SCOPE_AGENT) < ep)
                __builtin_amdgcn_s_sleep(1);
        __syncthreads();
        if (tid == 0) __threadfence();
        __syncthreads();
    };

    for (int c = 0; c < 3; ++c) {
        const int t0 = c * 64;
        const int t1 = (t0 + 64 < T_) ? t0 + 64 : T_;
        // ---- chunk wait: tags[0] >= t1+1 proves xhist[<=t1] complete;
        //      final chunk needs all 16 tags == 150.
        if (t1 < T_) {
            if (tid == 0)
                while (__hip_atomic_load(&tags[0], __ATOMIC_RELAXED,
                                         __HIP_MEMORY_SCOPE_AGENT) < t1 + 1)
                    __builtin_amdgcn_s_sleep(127);
        } else {
            if (tid < DB_)
                while (__hip_atomic_load(&tags[tid], __ATOMIC_RELAXED,
                                         __HIP_MEMORY_SCOPE_AGENT) < T_)
                    __builtin_amdgcn_s_sleep(127);
        }
        __syncthreads();

        // ======== S1: mapped = h @ Whm^T  (rows (t,b), fp16 out) ========
        for (int job = wid; job < 512; job += NW_) {
            const int t = t0 + (job >> 3);
            if (t >= t1) continue;
            const int n0 = (job & 7) * 64;
            f32x4 acc0 = {0.f,0.f,0.f,0.f}, acc1 = {0.f,0.f,0.f,0.f};
            const int mh = wv >> 2, nt = wv & 3;
            for (int kb = 0; kb < 512; kb += 32) {
                {   // A: h rows from xhist (atomic fp16)
                    int b = tid >> 3, s = tid & 7;
                    ull v = aload(&xhist[(size_t)(t + 1) * 8192 + b * 128 + kb / 4 + s]);
                    *(ull*)&As[b][s * 4] = v;
                }
                {   // B: Whm rows n0.. (fp32 cast)
                    int n = tid >> 3, s = tid & 7;
                    float4 w = *(const float4*)(Whm + (size_t)(n0 + n) * 512 + kb + s * 4);
                    f16x4 p = {(f16)w.x, (f16)w.y, (f16)w.z, (f16)w.w};
                    *(f16x4*)&Bs[n][s * 4] = p;
                }
                __syncthreads();
                f16x8 a0 = *(const f16x8*)&As[(2 * mh) * 16 + ln15][lnk8];
                f16x8 a1 = *(const f16x8*)&As[(2 * mh + 1) * 16 + ln15][lnk8];
                f16x8 bf = *(const f16x8*)&Bs[nt * 16 + ln15][lnk8];
                acc0 = __builtin_amdgcn_mfma_f32_16x16x32_f16(a0, bf, acc0, 0, 0, 0);
                acc1 = __builtin_amdgcn_mfma_f32_16x16x32_f16(a1, bf, acc1, 0, 0, 0);
                __syncthreads();
            }
            #pragma unroll
            for (int i = 0; i < 4; ++i) {
                int b0r = (2 * mh) * 16 + lr4 + i, b1r = (2 * mh + 1) * 16 + lr4 + i;
                int n = n0 + nt * 16 + ln15;
                stageA[((size_t)t * 64 + b0r) * 512 + n] = (f16)acc0[i];
                stageA[((size_t)t * 64 + b1r) * 512 + n] = (f16)acc1[i];
            }
        }
        wbar(++epoch);

        // ======== S2: S = mapped @ cnn[b]^T, softmax -> attP ========
        for (int b = wid; b < 64; b += NW_) {
            const float* cnnb = cnn + (size_t)b * L_ * H_;
            const int mh = wv >> 2, nq = wv & 3;
            f32x4 acc[2][4] = {};
            for (int kb = 0; kb < H_; kb += 32) {
                {   // A: mapped f16 rows (t0+t', b)
                    int tp = tid >> 3, s = tid & 7;
                    ull v = 0ull;
                    if (t0 + tp < t1)
                        v = *(const ull*)(stageA + ((size_t)(t0 + tp) * 64 + b) * 512 + kb + s * 4);
                    *(ull*)&As[tp][s * 4] = v;
                }
                {   // B: cnn[b] all 256 rows (fp32 cast)
                    int br = tid >> 1, bc16 = (tid & 1) * 16;
                    const float* src = cnnb + (size_t)br * H_ + kb + bc16;
                    float4 w0 = *(const float4*)(src);
                    float4 w1 = *(const float4*)(src + 4);
                    float4 w2 = *(const float4*)(src + 8);
                    float4 w3 = *(const float4*)(src + 12);
                    f16x8 p0 = {(f16)w0.x, (f16)w0.y, (f16)w0.z, (f16)w0.w,
                                (f16)w1.x, (f16)w1.y, (f16)w1.z, (f16)w1.w};
                    f16x8 p1 = {(f16)w2.x, (f16)w2.y, (f16)w2.z, (f16)w2.w,
                                (f16)w3.x, (f16)w3.y, (f16)w3.z, (f16)w3.w};
                    *(f16x8*)&Bs[br][bc16]     = p0;
                    *(f16x8*)&Bs[br][bc16 + 8] = p1;
                }
                __syncthreads();
                f16x8 a0 = *(const f16x8*)&As[(2 * mh) * 16 + ln15][lnk8];
                f16x8 a1 = *(const f16x8*)&As[(2 * mh + 1) * 16 + ln15][lnk8];
                #pragma unroll
                for (int nj = 0; nj < 4; ++nj) {
                    f16x8 bf = *(const f16x8*)&Bs[(nq * 4 + nj) * 16 + ln15][lnk8];
                    acc[0][nj] = __builtin_amdgcn_mfma_f32_16x16x32_f16(a0, bf, acc[0][nj], 0, 0, 0);
                    acc[1][nj] = __builtin_amdgcn_mfma_f32_16x16x32_f16(a1, bf, acc[1][nj], 0, 0, 0);
                }
                __syncthreads();
            }
            #pragma unroll
            for (int mi = 0; mi < 2; ++mi)
                #pragma unroll
                for (int nj = 0; nj < 4; ++nj)
                    #pragma unroll
                    for (int i = 0; i < 4; ++i)
                        sl[(2 * mh + mi) * 16 + lr4 + i][(nq * 4 + nj) * 16 + ln15]
                            = acc[mi][nj][i];
            __syncthreads();
            #pragma unroll
            for (int rr = 0; rr < 8; ++rr) {
                int r = wv * 8 + rr;
                int t = t0 + r;
                if (t < t1) {
                    float4 v = *(const float4*)&sl[r][ln * 4];
                    float mx = fmaxf(fmaxf(v.x, v.y), fmaxf(v.z, v.w));
                    #pragma unroll
                    for (int off = 32; off; off >>= 1) mx = fmaxf(mx, __shfl_xor(mx, off));
                    float e0 = expf(v.x - mx), e1 = expf(v.y - mx);
                    float e2 = expf(v.z - mx), e3 = expf(v.w - mx);
                    float s = e0 + e1 + e2 + e3;
                    #pragma unroll
                    for (int off = 32; off; off >>= 1) s += __shfl_xor(s, off);
                    float inv = 1.f / s;
                    f16x4 p = {(f16)(e0 * inv), (f16)(e1 * inv),
                               (f16)(e2 * inv), (f16)(e3 * inv)};
                    *(f16x4*)(attP + ((size_t)b * T_ + t) * L_ + ln * 4) = p;
                }
            }
            __syncthreads();
        }
        wbar(++epoch);

        // ======== S3: ctx = P @ cnn[b] -> stageA (overwrite) ========
        for (int job = wid; job < 512; job += NW_) {
            const int b = job >> 3;
            const int n0 = (job & 7) * 64;
            const float* cnnb = cnn + (size_t)b * L_ * H_;
            const int mh = wv >> 2, nt = wv & 3;
            f32x4 acc0 = {0.f,0.f,0.f,0.f}, acc1 = {0.f,0.f,0.f,0.f};
            for (int kb = 0; kb < L_; kb += 32) {
                {   // A: attP f16 rows t'
                    int tp = tid >> 3, s = tid & 7;
                    ull v = 0ull;
                    if (t0 + tp < t1)
                        v = *(const ull*)(attP + ((size_t)b * T_ + t0 + tp) * L_ + kb + s * 4);
                    *(ull*)&As[tp][s * 4] = v;
                }
                {   // B transposed: Bs[n][k] = cnn[b][kb+k][n0+n]
                    int br = tid >> 4, nc = (tid & 15) * 4;
                    float4 w = *(const float4*)(cnnb + (size_t)(kb + br) * H_ + n0 + nc);
                    Bs[nc + 0][br] = (f16)w.x; Bs[nc + 1][br] = (f16)w.y;
                    Bs[nc + 2][br] = (f16)w.z; Bs[nc + 3][br] = (f16)w.w;
                }
                __syncthreads();
                f16x8 a0 = *(const f16x8*)&As[(2 * mh) * 16 + ln15][lnk8];
                f16x8 a1 = *(const f16x8*)&As[(2 * mh + 1) * 16 + ln15][lnk8];
                f16x8 bf = *(const f16x8*)&Bs[nt * 16 + ln15][lnk8];
                acc0 = __builtin_amdgcn_mfma_f32_16x16x32_f16(a0, bf, acc0, 0, 0, 0);
                acc1 = __builtin_amdgcn_mfma_f32_16x16x32_f16(a1, bf, acc1, 0, 0, 0);
                __syncthreads();
            }
            #pragma unroll
            for (int i = 0; i < 4; ++i) {
                int tp0 = (2 * mh) * 16 + lr4 + i, tp1 = (2 * mh + 1) * 16 + lr4 + i;
                int n = n0 + nt * 16 + ln15;
                if (t0 + tp0 < t1)
                    stageA[((size_t)(t0 + tp0) * 64 + b) * 512 + n] = (f16)acc0[i];
                if (t0 + tp1 < t1)
                    stageA[((size_t)(t0 + tp1) * 64 + b) * 512 + n] = (f16)acc1[i];
            }
        }
        wbar(++epoch);

        // ======== S4: outv = [ctx | h] @ Wom^T  (K=1024) ========
        for (int job = wid; job < 512; job += NW_) {
            const int t = t0 + (job >> 3);
            if (t >= t1) continue;
            const int n0 = (job & 7) * 64;
            const int mh = wv >> 2, nt = wv & 3;
            f32x4 acc0 = {0.f,0.f,0.f,0.f}, acc1 = {0.f,0.f,0.f,0.f};
            for (int kb = 0; kb < 1024; kb += 32) {
                {   // A: ctx (stageA) for k<512, h (xhist) for k>=512
                    int b = tid >> 3, s = tid & 7;
                    ull v;
                    if (kb < 512)
                        v = *(const ull*)(stageA + ((size_t)t * 64 + b) * 512 + kb + s * 4);
                    else
                        v = aload(&xhist[(size_t)(t + 1) * 8192 + b * 128 + (kb - 512) / 4 + s]);
                    *(ull*)&As[b][s * 4] = v;
                }
                {   // B: Wom rows n0.. (fp32 cast), K=1024
                    int n = tid >> 3, s = tid & 7;
                    float4 w = *(const float4*)(Wom + (size_t)(n0 + n) * 1024 + kb + s * 4);
                    f16x4 p = {(f16)w.x, (f16)w.y, (f16)w.z, (f16)w.w};
                    *(f16x4*)&Bs[n][s * 4] = p;
                }
                __syncthreads();
                f16x8 a0 = *(const f16x8*)&As[(2 * mh) * 16 + ln15][lnk8];
                f16x8 a1 = *(const f16x8*)&As[(2 * mh + 1) * 16 + ln15][lnk8];
                f16x8 bf = *(const f16x8*)&Bs[nt * 16 + ln15][lnk8];
                acc0 = __builtin_amdgcn_mfma_f32_16x16x32_f16(a0, bf, acc0, 0, 0, 0);
                acc1 = __builtin_amdgcn_mfma_f32_16x16x32_f16(a1, bf, acc1, 0, 0, 0);
                __syncthreads();
            }
            #pragma unroll
            for (int i = 0; i < 4; ++i) {
                int b0r = (2 * mh) * 16 + lr4 + i, b1r = (2 * mh + 1) * 16 + lr4 + i;
                int n = n0 + nt * 16 + ln15;
                outv16[((size_t)t * 64 + b0r) * 512 + n] = (f16)acc0[i];
                outv16[((size_t)t * 64 + b1r) * 512 + n] = (f16)acc1[i];
            }
        }
        wbar(++epoch);

        // ======== S5: logits = outv @ Wlg^T + bias -> d_out (b,t) ========
        for (int job = wid; job < 1024; job += NW_) {
            const int t = t0 + (job >> 4);
            if (t >= t1) continue;
            const int n0 = (job & 15) * 64;
            const int mh = wv >> 2, nt = wv & 3;
            f32x4 acc0 = {0.f,0.f,0.f,0.f}, acc1 = {0.f,0.f,0.f,0.f};
            for (int kb = 0; kb < 512; kb += 32) {
                {   // A: outv f16
                    int b = tid >> 3, s = tid & 7;
                    ull v = *(const ull*)(outv16 + ((size_t)t * 64 + b) * 512 + kb + s * 4);
                    *(ull*)&As[b][s * 4] = v;
                }
                {   // B: Wlg rows (guard >= 1000 -> 0)
                    int n = tid >> 3, s = tid & 7;
                    f16x4 p = {(f16)0.f, (f16)0.f, (f16)0.f, (f16)0.f};
                    if (n0 + n < V_) {
                        float4 w = *(const float4*)(Wlg + (size_t)(n0 + n) * 512 + kb + s * 4);
                        p = (f16x4){(f16)w.x, (f16)w.y, (f16)w.z, (f16)w.w};
                    }
                    *(f16x4*)&Bs[n][s * 4] = p;
                }
                __syncthreads();
                f16x8 a0 = *(const f16x8*)&As[(2 * mh) * 16 + ln15][lnk8];
                f16x8 a1 = *(const f16x8*)&As[(2 * mh + 1) * 16 + ln15][lnk8];
                f16x8 bf = *(const f16x8*)&Bs[nt * 16 + ln15][lnk8];
                acc0 = __builtin_amdgcn_mfma_f32_16x16x32_f16(a0, bf, acc0, 0, 0, 0);
                acc1 = __builtin_amdgcn_mfma_f32_16x16x32_f16(a1, bf, acc1, 0, 0, 0);
                __syncthreads();
            }
            int gn = n0 + nt * 16 + ln15;
            if (gn < V_) {
                float bias = b_logit[gn];
                #pragma unroll
                for (int i = 0; i < 4; ++i) {
                    int b0r = (2 * mh) * 16 + lr4 + i, b1r = (2 * mh + 1) * 16 + lr4 + i;
                    out[((size_t)b0r * T_ + t) * V_ + gn] = acc0[i] + bias;
                    out[((size_t)b1r * T_ + t) * V_ + gn] = acc1[i] + bias;
                }
            }
        }
        wbar(++epoch);

        // ======== S6: log_softmax rows (one row per wave) ========
        for (int j = wid * 8 + wv; j < (t1 - t0) * 64; j += NW_ * 8) {
            const int b = j & 63, tt = t0 + (j >> 6);
            float* p = out + ((size_t)b * T_ + tt) * V_;
            float mx = -INFINITY;
            for (int i = ln; i < V_; i += 64) mx = fmaxf(mx, p[i]);
            #pragma unroll
            for (int off = 32; off; off >>= 1) mx = fmaxf(mx, __shfl_xor(mx, off));
            float s = 0.f;
            for (int i = ln; i < V_; i += 64) s += expf(p[i] - mx);
            #pragma unroll
            for (int off = 32; off; off >>= 1) s += __shfl_xor(s, off);
            float lse = mx + logf(s);
            for (int i = ln; i < V_; i += 64) p[i] -= lse;
        }
        // no barrier needed: next chunk touches disjoint rows
    }
}

// ---------------- fp16-MFMA NT GEMM (pregate table)
template<bool RELU_A>
__global__ __launch_bounds__(256) void gemm16_nt(
    const float* __restrict__ A1, const float* __restrict__ Bm,
    const float* __restrict__ bias1, const float* __restrict__ bias2,
    float* __restrict__ C, int M, int N, int K)
{
    __shared__ f16 As[64][40];
    __shared__ f16 Bs[64][40];
    const int tid = threadIdx.x;
    const int m0 = blockIdx.x * 64, n0 = blockIdx.y * 64;
    const int ln = tid & 63, wv = tid >> 6;
    const int lr = tid >> 2, lc8 = (tid & 3) * 8;
    f32x4 acc[4] = {};

    for (int kb = 0; kb < K; kb += 32) {
        int gm = m0 + lr;
        float4 a0 = make_float4(0.f, 0.f, 0.f, 0.f), a1 = a0;
        if (gm < M) {
            a0 = *(const float4*)(A1 + (size_t)gm * K + kb + lc8);
            a1 = *(const float4*)(A1 + (size_t)gm * K + kb + lc8 + 4);
        }
        if (RELU_A) {
            a0.x = fmaxf(a0.x, 0.f); a0.y = fmaxf(a0.y, 0.f);
            a0.z = fmaxf(a0.z, 0.f); a0.w = fmaxf(a0.w, 0.f);
            a1.x = fmaxf(a1.x, 0.f); a1.y = fmaxf(a1.y, 0.f);
            a1.z = fmaxf(a1.z, 0.f); a1.w = fmaxf(a1.w, 0.f);
        }
        f16x8 av = {(f16)a0.x, (f16)a0.y, (f16)a0.z, (f16)a0.w,
                    (f16)a1.x, (f16)a1.y, (f16)a1.z, (f16)a1.w};
        *(f16x8*)&As[lr][lc8] = av;

        int gn = n0 + lr;
        float4 b0 = make_float4(0.f, 0.f, 0.f, 0.f), b1 = b0;
        if (gn < N) {
            b0 = *(const float4*)(Bm + (size_t)gn * K + kb + lc8);
            b1 = *(const float4*)(Bm + (size_t)gn * K + kb + lc8 + 4);
        }
        f16x8 bv = {(f16)b0.x, (f16)b0.y, (f16)b0.z, (f16)b0.w,
                    (f16)b1.x, (f16)b1.y, (f16)b1.z, (f16)b1.w};
        *(f16x8*)&Bs[lr][lc8] = bv;
        __syncthreads();

        f16x8 af = *(const f16x8*)&As[wv * 16 + (ln & 15)][(ln >> 4) * 8];
        #pragma unroll
        for (int ntt = 0; ntt < 4; ++ntt) {
            f16x8 bf = *(const f16x8*)&Bs[ntt * 16 + (ln & 15)][(ln >> 4) * 8];
            acc[ntt] = __builtin_amdgcn_mfma_f32_16x16x32_f16(af, bf, acc[ntt], 0, 0, 0);
        }
        __syncthreads();
    }

    #pragma unroll
    for (int ntt = 0; ntt < 4; ++ntt)
        #pragma unroll
        for (int i = 0; i < 4; ++i) {
            int gm = m0 + wv * 16 + (ln >> 4) * 4 + i;
            int gn = n0 + ntt * 16 + (ln & 15);
            if (gm < M && gn < N) {
                float v = acc[ntt][i];
                if (bias1) v += bias1[gn];
                if (bias2) v += bias2[gn];
                C[(size_t)gm * N + gn] = v;
            }
        }
}

extern "C" void kernel_launch(void* const* d_in, const int* in_sizes, int n_in,
                              void* d_out, int out_size, void* d_ws, size_t ws_size,
                              hipStream_t stream)
{
    const float* cnn     = (const float*)d_in[0];
    const int*   seq     = (const int*)d_in[1];
    const float* embed   = (const float*)d_in[2];
    const float* W_ih    = (const float*)d_in[3];
    const float* b_ih    = (const float*)d_in[4];
    const float* W_hh    = (const float*)d_in[5];
    const float* b_hh    = (const float*)d_in[6];
    const float* W_hm    = (const float*)d_in[7];
    const float* W_om    = (const float*)d_in[8];
    const float* W_logit = (const float*)d_in[9];
    const float* b_logit = (const float*)d_in[10];
    float* out = (float*)d_out;

    char* ws = (char*)d_ws;
    float* G      = (float*)ws;                       //  8,192,000 B
    ull*   xhist  = (ull*)(ws + 8192000);             //  9,895,936 B (151*8192*8)
    f16*   stageA = (f16*)(ws + 18087936);            //  9,830,400 B
    f16*   attP   = (f16*)(ws + 27918336);            //  4,915,200 B
    f16*   outv16 = (f16*)(ws + 32833536);            //  9,830,400 B
    int*   tags   = (int*)(ws + 42663936);            //         64 B
    int*   wflags = (int*)(ws + 42664000);            //        960 B

    hipMemsetAsync(tags, 0, DB_ * sizeof(int), stream);
    hipMemsetAsync(wflags, 0, NW_ * sizeof(int), stream);
    hipMemsetAsync(xhist, 0, 8192 * sizeof(ull), stream);   // h^0 = 0

    // pregate table: G[v][:] = relu(embed[v]) @ W_ih^T + b_ih + b_hh
    gemm16_nt<true><<<dim3(16, 32), 256, 0, stream>>>(
        embed, W_ih, b_ih, b_hh, G, V_, G4_, E_);

    // mega-kernel: 16 producers + 240 workers (t-chunked batched phase-2)
    mega_decoder<<<DB_ + NW_, 512, 0, stream>>>(
        seq, G, W_hh, cnn, W_hm, W_om, W_logit, b_logit,
        xhist, tags, wflags, stageA, attP, outv16, out);
}